// Round 1
// baseline (468.550 us; speedup 1.0000x reference)
//
#include <hip/hip_runtime.h>
#include <math.h>

// Problem constants (B=8, N=1024, D=256, C=8192)
#define QROWS 8192          // B*N query rows
#define DDIM  256
#define CCNT  8192
#define BM    128           // rows per block tile
#define BN    128           // cols (codes) per block tile
#define KT    16            // k tile
#define CBLKS (CCNT / BN)   // 64 column blocks

// ---------------- Kernel 1: inverse L2 norm of each codebook row ----------------
__global__ void k_invnorm(const float* __restrict__ e, float* __restrict__ invn) {
    const int row  = blockIdx.x * 4 + (threadIdx.x >> 6);
    const int lane = threadIdx.x & 63;
    const float4 v = *reinterpret_cast<const float4*>(e + row * DDIM + lane * 4);
    float s = v.x * v.x + v.y * v.y + v.z * v.z + v.w * v.w;
    #pragma unroll
    for (int off = 32; off; off >>= 1) s += __shfl_down(s, off);
    if (lane == 0) invn[row] = 1.0f / fmaxf(sqrtf(s), 1e-12f);
}

// ---------------- Kernel 2: fused f32 GEMM (x · e^T) + per-tile argmax ----------------
__launch_bounds__(256)
__global__ void k_gemm_argmax(const float* __restrict__ x, const float* __restrict__ e,
                              const float* __restrict__ invn,
                              float* __restrict__ pval, int* __restrict__ pidx) {
    __shared__ float As[BM][KT + 4];   // +4 pad keeps 16B alignment, breaks pow2 stride
    __shared__ float Bs[BN][KT + 4];
    __shared__ float rv[BM][16];
    __shared__ int   ri[BM][16];

    const int bx = blockIdx.x;          // column (code) block
    const int by = blockIdx.y;          // row (query) block
    const int tid = threadIdx.x;
    const int tx = tid & 15, ty = tid >> 4;
    const int n0 = by * BM, c0 = bx * BN;

    float acc[8][8] = {};

    for (int k0 = 0; k0 < DDIM; k0 += KT) {
        // stage A and B tiles: 512 float4 each, 2 per thread
        #pragma unroll
        for (int i = 0; i < 2; ++i) {
            const int f   = tid + 256 * i;     // 0..511
            const int row = f >> 2;
            const int q   = (f & 3) * 4;
            const float4 a = *reinterpret_cast<const float4*>(x + (size_t)(n0 + row) * DDIM + k0 + q);
            *reinterpret_cast<float4*>(&As[row][q]) = a;
            const float4 b = *reinterpret_cast<const float4*>(e + (size_t)(c0 + row) * DDIM + k0 + q);
            *reinterpret_cast<float4*>(&Bs[row][q]) = b;
        }
        __syncthreads();

        #pragma unroll
        for (int kg = 0; kg < KT / 4; ++kg) {
            float4 b4[8];
            #pragma unroll
            for (int j = 0; j < 8; ++j)
                b4[j] = *reinterpret_cast<const float4*>(&Bs[tx + 16 * j][kg * 4]);
            #pragma unroll
            for (int i = 0; i < 8; ++i) {
                const float4 a4 = *reinterpret_cast<const float4*>(&As[ty + 16 * i][kg * 4]);
                #pragma unroll
                for (int j = 0; j < 8; ++j) {
                    acc[i][j] = fmaf(a4.x, b4[j].x, acc[i][j]);
                    acc[i][j] = fmaf(a4.y, b4[j].y, acc[i][j]);
                    acc[i][j] = fmaf(a4.z, b4[j].z, acc[i][j]);
                    acc[i][j] = fmaf(a4.w, b4[j].w, acc[i][j]);
                }
            }
        }
        __syncthreads();
    }

    // scale by code inverse-norm, per-thread argmax over its 8 columns
    float inv[8];
    #pragma unroll
    for (int j = 0; j < 8; ++j) inv[j] = invn[c0 + tx + 16 * j];

    #pragma unroll
    for (int i = 0; i < 8; ++i) {
        float bv = -INFINITY; int bc = 0;
        #pragma unroll
        for (int j = 0; j < 8; ++j) {
            const float v = acc[i][j] * inv[j];
            const int   c = c0 + tx + 16 * j;
            if (v > bv || (v == bv && c < bc)) { bv = v; bc = c; }
        }
        rv[ty + 16 * i][tx] = bv;
        ri[ty + 16 * i][tx] = bc;
    }
    __syncthreads();

    // 128 threads: reduce the 16 per-thread candidates of one row
    if (tid < BM) {
        float bv = -INFINITY; int bc = 0;
        #pragma unroll
        for (int t = 0; t < 16; ++t) {
            const float v = rv[tid][t];
            const int   c = ri[tid][t];
            if (v > bv || (v == bv && c < bc)) { bv = v; bc = c; }
        }
        const int row = n0 + tid;
        pval[(size_t)row * CBLKS + bx] = bv;
        pidx[(size_t)row * CBLKS + bx] = bc;
    }
}

// ---------------- Kernel 3: reduce partials, write idx (as float) + gather rows ----------------
__global__ void k_reduce_gather(const float* __restrict__ pval, const int* __restrict__ pidx,
                                const float* __restrict__ e, float* __restrict__ out) {
    const int row = blockIdx.x;
    const int t   = threadIdx.x;     // 64 threads = 1 wave; CBLKS == 64
    float v = pval[(size_t)row * CBLKS + t];
    int   c = pidx[(size_t)row * CBLKS + t];
    #pragma unroll
    for (int off = 32; off; off >>= 1) {
        const float ov = __shfl_down(v, off);
        const int   oc = __shfl_down(c, off);
        if (ov > v || (ov == v && oc < c)) { v = ov; c = oc; }
    }
    c = __shfl(c, 0);                // broadcast winning index
    if (t == 0) out[(size_t)QROWS * DDIM + row] = (float)c;
    const float4 val = *reinterpret_cast<const float4*>(e + (size_t)c * DDIM + t * 4);
    *reinterpret_cast<float4*>(out + (size_t)row * DDIM + t * 4) = val;
}

extern "C" void kernel_launch(void* const* d_in, const int* in_sizes, int n_in,
                              void* d_out, int out_size, void* d_ws, size_t ws_size,
                              hipStream_t stream) {
    const float* x = (const float*)d_in[0];   // [8,1024,256]
    const float* e = (const float*)d_in[1];   // [1,8192,256]
    float* out = (float*)d_out;               // [Q*D quantize][Q idx-as-float]
    char* ws = (char*)d_ws;

    float* invn = (float*)ws;                                   // 32 KB
    float* pval = (float*)(ws + 32 * 1024);                     // 2 MB
    int*   pidx = (int*)(ws + 32 * 1024 + (size_t)QROWS * CBLKS * 4); // 2 MB

    k_invnorm<<<CCNT / 4, 256, 0, stream>>>(e, invn);
    dim3 g2(CBLKS, QROWS / BM);
    k_gemm_argmax<<<g2, 256, 0, stream>>>(x, e, invn, pval, pidx);
    k_reduce_gather<<<QROWS, 64, 0, stream>>>(pval, pidx, e, out);
}

// Round 2
// 111.473 us; speedup vs baseline: 4.2033x; 4.2033x over previous
//
#include <hip/hip_runtime.h>
#include <math.h>

// B=8, N=1024, D=256, C=8192
#define QROWS 8192
#define DDIM  256
#define CCNT  8192
#define BM    128
#define BN    128
#define BK    32
#define CBLKS (CCNT / BN)    // 64
#define KSTEPS (DDIM / BK)   // 8

typedef __attribute__((ext_vector_type(4))) float f32x4;
typedef __attribute__((ext_vector_type(8))) short bf16x8;

__device__ __forceinline__ unsigned short f2bf(float f) {
    unsigned u = __float_as_uint(f);
    u += 0x7fffu + ((u >> 16) & 1u);          // round-to-nearest-even
    return (unsigned short)(u >> 16);
}

// monotone (value, lowest-index-wins) packing into one u64
__device__ __forceinline__ unsigned long long packkey(float v, int col) {
    unsigned u = __float_as_uint(v);
    u = (u & 0x80000000u) ? ~u : (u | 0x80000000u);
    return ((unsigned long long)u << 32) | (unsigned)(~col);
}

// ---------- prep: x f32 -> bf16 ----------
__global__ void k_prep_x(const float* __restrict__ x, unsigned short* __restrict__ xb) {
    const int i = (blockIdx.x * 256 + threadIdx.x) * 8;
    const float4 f0 = *reinterpret_cast<const float4*>(x + i);
    const float4 f1 = *reinterpret_cast<const float4*>(x + i + 4);
    uint4 o;
    o.x = f2bf(f0.x) | ((unsigned)f2bf(f0.y) << 16);
    o.y = f2bf(f0.z) | ((unsigned)f2bf(f0.w) << 16);
    o.z = f2bf(f1.x) | ((unsigned)f2bf(f1.y) << 16);
    o.w = f2bf(f1.z) | ((unsigned)f2bf(f1.w) << 16);
    *reinterpret_cast<uint4*>(xb + i) = o;
}

// ---------- prep: e -> l2-normalized bf16 ----------
__global__ void k_prep_e(const float* __restrict__ e, unsigned short* __restrict__ eb) {
    const int row  = blockIdx.x * 4 + (threadIdx.x >> 6);
    const int lane = threadIdx.x & 63;
    const float4 v = *reinterpret_cast<const float4*>(e + (size_t)row * DDIM + lane * 4);
    float s = v.x * v.x + v.y * v.y + v.z * v.z + v.w * v.w;
    #pragma unroll
    for (int off = 1; off < 64; off <<= 1) s += __shfl_xor(s, off);
    const float inv = 1.0f / fmaxf(sqrtf(s), 1e-12f);
    ushort4 o;
    o.x = f2bf(v.x * inv); o.y = f2bf(v.y * inv);
    o.z = f2bf(v.z * inv); o.w = f2bf(v.w * inv);
    *reinterpret_cast<ushort4*>(eb + (size_t)row * DDIM + lane * 4) = o;
}

#define GLOAD_LDS(g, s) \
    __builtin_amdgcn_global_load_lds((const __attribute__((address_space(1))) void*)(g), \
                                     (__attribute__((address_space(3))) void*)(s), 16, 0, 0)

// ---------- bf16 MFMA GEMM + per-row top-2 per block ----------
__launch_bounds__(256)
__global__ void k_gemm(const unsigned short* __restrict__ xb,
                       const unsigned short* __restrict__ eb,
                       unsigned long long* pout /* aliases d_out, no restrict elsewhere */) {
    __shared__ unsigned short Atile[BM * BK];   // 8 KB, linear [row][k]
    __shared__ unsigned short Btile[BN * BK];   // 8 KB
    __shared__ unsigned long long top2[BM][2][2]; // 4 KB

    const int tid = threadIdx.x;
    const int w = tid >> 6, l = tid & 63;
    const int wr = w >> 1, wc = w & 1;        // wave tile: rows wr*64, cols wc*64
    const int lg = l >> 4, lr = l & 15;
    const int bx = blockIdx.x, by = blockIdx.y;
    const int n0 = by * BM, c0 = bx * BN;

    const f32x4 zero = {0.f, 0.f, 0.f, 0.f};
    f32x4 acc[4][4];
    #pragma unroll
    for (int i = 0; i < 4; ++i)
        #pragma unroll
        for (int j = 0; j < 4; ++j) acc[i][j] = zero;

    // staging: chunk c (0..511) of a tile -> LDS byte c*16; row=c>>2, off=(c&3)*16
    const char* gax0 = (const char*)xb + (size_t)(n0 + (tid >> 2)) * 512 + (tid & 3) * 16;
    const char* gax1 = gax0 + 64 * 512;   // row +64
    const char* gae0 = (const char*)eb + (size_t)(c0 + (tid >> 2)) * 512 + (tid & 3) * 16;
    const char* gae1 = gae0 + 64 * 512;
    unsigned short* la0 = &Atile[(size_t)(0 * 256 + w * 64) * 8];
    unsigned short* la1 = &Atile[(size_t)(1 * 256 + w * 64) * 8];
    unsigned short* lb0 = &Btile[(size_t)(0 * 256 + w * 64) * 8];
    unsigned short* lb1 = &Btile[(size_t)(1 * 256 + w * 64) * 8];

    for (int s = 0; s < KSTEPS; ++s) {
        const int kb = s * 64;                 // byte offset within a 512 B row
        GLOAD_LDS(gax0 + kb, la0);
        GLOAD_LDS(gax1 + kb, la1);
        GLOAD_LDS(gae0 + kb, lb0);
        GLOAD_LDS(gae1 + kb, lb1);
        __syncthreads();                        // drains vmcnt before barrier

        bf16x8 a[4], b[4];
        const int koff = lg * 8;
        #pragma unroll
        for (int mi = 0; mi < 4; ++mi)
            a[mi] = *reinterpret_cast<const bf16x8*>(&Atile[(wr * 64 + mi * 16 + lr) * BK + koff]);
        #pragma unroll
        for (int nj = 0; nj < 4; ++nj)
            b[nj] = *reinterpret_cast<const bf16x8*>(&Btile[(wc * 64 + nj * 16 + lr) * BK + koff]);
        #pragma unroll
        for (int mi = 0; mi < 4; ++mi)
            #pragma unroll
            for (int nj = 0; nj < 4; ++nj)
                acc[mi][nj] = __builtin_amdgcn_mfma_f32_16x16x32_bf16(a[mi], b[nj], acc[mi][nj], 0, 0, 0);
        __syncthreads();
    }

    // epilogue: per-row top-2 over this block's 128 cols
    // C/D layout: row = mi*16 + lg*4 + r, col = nj*16 + lr (within wave tile)
    #pragma unroll
    for (int mi = 0; mi < 4; ++mi) {
        #pragma unroll
        for (int r = 0; r < 4; ++r) {
            unsigned long long t1 = 0ull, t2 = 0ull;
            #pragma unroll
            for (int nj = 0; nj < 4; ++nj) {
                const unsigned long long k = packkey(acc[mi][nj][r], c0 + wc * 64 + nj * 16 + lr);
                if (k > t1) { t2 = t1; t1 = k; } else if (k > t2) { t2 = k; }
            }
            #pragma unroll
            for (int off = 1; off < 16; off <<= 1) {
                const unsigned long long o1 = __shfl_xor(t1, off);
                const unsigned long long o2 = __shfl_xor(t2, off);
                const unsigned long long n1 = t1 > o1 ? t1 : o1;
                const unsigned long long lo = t1 > o1 ? o1 : t1;
                const unsigned long long mx2 = t2 > o2 ? t2 : o2;
                t1 = n1;
                t2 = lo > mx2 ? lo : mx2;
            }
            if (lr == 0) {
                const int rloc = wr * 64 + mi * 16 + lg * 4 + r;
                top2[rloc][wc][0] = t1;
                top2[rloc][wc][1] = t2;
            }
        }
    }
    __syncthreads();

    if (tid < BM) {
        const unsigned long long a1 = top2[tid][0][0], a2 = top2[tid][0][1];
        const unsigned long long b1 = top2[tid][1][0], b2 = top2[tid][1][1];
        const unsigned long long m1 = a1 > b1 ? a1 : b1;
        const unsigned long long lo = a1 > b1 ? b1 : a1;
        const unsigned long long mx = a2 > b2 ? a2 : b2;
        const unsigned long long m2 = lo > mx ? lo : mx;
        const size_t row = (size_t)(n0 + tid);
        pout[row * 128 + bx * 2 + 0] = m1;     // byte offset row*1024 + bx*16
        pout[row * 128 + bx * 2 + 1] = m2;
    }
}

// ---------- fixup: global top-4 candidates -> exact f32 -> argmax + gather ----------
__global__ void k_fixup(const unsigned long long* pk,  // == (u64*)d_out, intentionally no restrict
                        const float* __restrict__ x, const float* __restrict__ e,
                        float* out) {
    const int row = blockIdx.x;
    const int t   = threadIdx.x;   // 64 lanes
    const unsigned long long* pr = pk + (size_t)row * 128;
    unsigned long long k0 = pr[2 * t], k1 = pr[2 * t + 1];

    int cand[4];
    #pragma unroll
    for (int p = 0; p < 4; ++p) {
        unsigned long long m = k0 > k1 ? k0 : k1;
        #pragma unroll
        for (int off = 1; off < 64; off <<= 1) {
            const unsigned long long o = __shfl_xor(m, off);
            if (o > m) m = o;
        }
        cand[p] = (int)(~(unsigned)m) & (CCNT - 1);
        if (k0 == m) k0 = 0ull;
        if (k1 == m) k1 = 0ull;
    }

    const float4 xv = *reinterpret_cast<const float4*>(x + (size_t)row * DDIM + t * 4);
    float best = -INFINITY; int bc = 0x7fffffff;
    #pragma unroll
    for (int p = 0; p < 4; ++p) {
        const int c = cand[p];
        const float4 ev = *reinterpret_cast<const float4*>(e + (size_t)c * DDIM + t * 4);
        float d  = xv.x * ev.x + xv.y * ev.y + xv.z * ev.z + xv.w * ev.w;
        float ss = ev.x * ev.x + ev.y * ev.y + ev.z * ev.z + ev.w * ev.w;
        #pragma unroll
        for (int off = 1; off < 64; off <<= 1) {
            d  += __shfl_xor(d, off);
            ss += __shfl_xor(ss, off);
        }
        const float v = d * (1.0f / fmaxf(sqrtf(ss), 1e-12f));
        if (v > best || (v == best && c < bc)) { best = v; bc = c; }
    }

    if (t == 0) out[(size_t)QROWS * DDIM + row] = (float)bc;
    const float4 q = *reinterpret_cast<const float4*>(e + (size_t)bc * DDIM + t * 4);
    *reinterpret_cast<float4*>(out + (size_t)row * DDIM + t * 4) = q; // overwrites this row's partials only
}

extern "C" void kernel_launch(void* const* d_in, const int* in_sizes, int n_in,
                              void* d_out, int out_size, void* d_ws, size_t ws_size,
                              hipStream_t stream) {
    const float* x = (const float*)d_in[0];
    const float* e = (const float*)d_in[1];
    float* out = (float*)d_out;
    char* ws = (char*)d_ws;

    unsigned short* xb = (unsigned short*)ws;                          // 4 MB
    unsigned short* eb = (unsigned short*)(ws + (size_t)4 * 1024 * 1024); // 4 MB

    k_prep_x<<<QROWS * DDIM / (256 * 8), 256, 0, stream>>>(x, xb);
    k_prep_e<<<CCNT / 4, 256, 0, stream>>>(e, eb);
    dim3 g2(CBLKS, QROWS / BM);
    k_gemm<<<g2, 256, 0, stream>>>(xb, eb, (unsigned long long*)d_out);
    k_fixup<<<QROWS, 64, 0, stream>>>((const unsigned long long*)d_out, x, e, out);
}

// Round 3
// 71.407 us; speedup vs baseline: 6.5617x; 1.5611x over previous
//
#include <hip/hip_runtime.h>
#include <math.h>

// B=8, N=1024, D=256, C=8192
#define QROWS 8192
#define DDIM  256
#define CCNT  8192
#define BM    128
#define BN    128
#define BK    32
#define CBLKS (CCNT / BN)    // 64
#define KSTEPS (DDIM / BK)   // 8

typedef __attribute__((ext_vector_type(4))) float f32x4;
typedef __attribute__((ext_vector_type(8))) short bf16x8;

__device__ __forceinline__ unsigned short f2bf(float f) {
    unsigned u = __float_as_uint(f);
    u += 0x7fffu + ((u >> 16) & 1u);          // round-to-nearest-even
    return (unsigned short)(u >> 16);
}
__device__ __forceinline__ unsigned u32max(unsigned a, unsigned b) { return a > b ? a : b; }
__device__ __forceinline__ unsigned u32min(unsigned a, unsigned b) { return a < b ? a : b; }

// u32 key: 25-bit monotone float + 7-bit (127 - local_col); bigger = better, lower col wins ties
__device__ __forceinline__ unsigned key32(float v, unsigned enc) {
    unsigned u = __float_as_uint(v);
    unsigned s = (unsigned)((int)u >> 31);
    return ((u ^ (s | 0x80000000u)) & 0xFFFFFF80u) | enc;
}

// ---------- prep: x f32 -> bf16 ----------
__global__ void k_prep_x(const float* __restrict__ x, unsigned short* __restrict__ xb) {
    const int i = (blockIdx.x * 256 + threadIdx.x) * 8;
    const float4 f0 = *reinterpret_cast<const float4*>(x + i);
    const float4 f1 = *reinterpret_cast<const float4*>(x + i + 4);
    uint4 o;
    o.x = f2bf(f0.x) | ((unsigned)f2bf(f0.y) << 16);
    o.y = f2bf(f0.z) | ((unsigned)f2bf(f0.w) << 16);
    o.z = f2bf(f1.x) | ((unsigned)f2bf(f1.y) << 16);
    o.w = f2bf(f1.z) | ((unsigned)f2bf(f1.w) << 16);
    *reinterpret_cast<uint4*>(xb + i) = o;
}

// ---------- prep: e -> l2-normalized bf16 ----------
__global__ void k_prep_e(const float* __restrict__ e, unsigned short* __restrict__ eb) {
    const int row  = blockIdx.x * 4 + (threadIdx.x >> 6);
    const int lane = threadIdx.x & 63;
    const float4 v = *reinterpret_cast<const float4*>(e + (size_t)row * DDIM + lane * 4);
    float s = v.x * v.x + v.y * v.y + v.z * v.z + v.w * v.w;
    #pragma unroll
    for (int off = 1; off < 64; off <<= 1) s += __shfl_xor(s, off);
    const float inv = 1.0f / fmaxf(sqrtf(s), 1e-12f);
    ushort4 o;
    o.x = f2bf(v.x * inv); o.y = f2bf(v.y * inv);
    o.z = f2bf(v.z * inv); o.w = f2bf(v.w * inv);
    *reinterpret_cast<ushort4*>(eb + (size_t)row * DDIM + lane * 4) = o;
}

#define GLOAD_LDS(g, s) \
    __builtin_amdgcn_global_load_lds((const __attribute__((address_space(1))) void*)(g), \
                                     (__attribute__((address_space(3))) void*)(s), 16, 0, 0)

// ---------- bf16 MFMA GEMM (2-phase dbuf) + per-row top-2 per block ----------
__launch_bounds__(256)
__global__ void k_gemm(const unsigned short* __restrict__ xb,
                       const unsigned short* __restrict__ eb,
                       unsigned* pout /* aliases d_out */) {
    // union: staging dbuf (32 KB) / epilogue table [128][33] uint2 (33792 B)
    __shared__ __align__(16) char smem[33792];

    const int tid = threadIdx.x;
    const int w = tid >> 6, l = tid & 63;
    const int wr = w >> 1, wc = w & 1;        // wave tile: rows wr*64, cols wc*64
    const int lg = l >> 4, lr = l & 15;
    const int bx = blockIdx.x, by = blockIdx.y;
    const int n0 = by * BM, c0 = bx * BN;

    const f32x4 zero = {0.f, 0.f, 0.f, 0.f};
    f32x4 acc[4][4];
    #pragma unroll
    for (int i = 0; i < 4; ++i)
        #pragma unroll
        for (int j = 0; j < 4; ++j) acc[i][j] = zero;

    // staging addresses: chunk c (0..511) -> LDS byte c*16; row=c>>2, koff=(c&3)*16
    const char* gA = (const char*)xb + (size_t)(n0 + (tid >> 2)) * 512 + (tid & 3) * 16;
    const char* gB = (const char*)eb + (size_t)(c0 + (tid >> 2)) * 512 + (tid & 3) * 16;
    const int wb = w * 1024;   // wave-uniform LDS chunk base

    #define STAGE(buf, s) do {                                         \
        const int kb_ = (s) * 64;                                      \
        char* Ab_ = smem + (buf) * 8192 + wb;                          \
        char* Bb_ = smem + 16384 + (buf) * 8192 + wb;                  \
        GLOAD_LDS(gA + kb_, Ab_);                                      \
        GLOAD_LDS(gA + 64 * 512 + kb_, Ab_ + 4096);                    \
        GLOAD_LDS(gB + kb_, Bb_);                                      \
        GLOAD_LDS(gB + 64 * 512 + kb_, Bb_ + 4096);                    \
    } while (0)

    STAGE(0, 0);
    __syncthreads();

    #pragma unroll
    for (int s = 0; s < KSTEPS; ++s) {
        const int cur = s & 1;
        if (s + 1 < KSTEPS) STAGE(cur ^ 1, s + 1);   // prefetch next tile (other buffer)

        const unsigned short* At = (const unsigned short*)(smem + cur * 8192);
        const unsigned short* Bt = (const unsigned short*)(smem + 16384 + cur * 8192);
        bf16x8 a[4], b[4];
        const int koff = lg * 8;
        #pragma unroll
        for (int mi = 0; mi < 4; ++mi)
            a[mi] = *reinterpret_cast<const bf16x8*>(&At[(wr * 64 + mi * 16 + lr) * BK + koff]);
        #pragma unroll
        for (int nj = 0; nj < 4; ++nj)
            b[nj] = *reinterpret_cast<const bf16x8*>(&Bt[(wc * 64 + nj * 16 + lr) * BK + koff]);
        #pragma unroll
        for (int mi = 0; mi < 4; ++mi)
            #pragma unroll
            for (int nj = 0; nj < 4; ++nj)
                acc[mi][nj] = __builtin_amdgcn_mfma_f32_16x16x32_bf16(a[mi], b[nj], acc[mi][nj], 0, 0, 0);
        __syncthreads();   // drains stage loads (vmcnt 0) + frag reads; next iter safe
    }

    // ---- epilogue: per-lane top2-of-4 u32 keys -> LDS table -> per-row scan ----
    uint2* T = (uint2*)smem;                    // [128][33] padded
    const unsigned encbase = (unsigned)(127 - wc * 64 - lr);
    #pragma unroll
    for (int mi = 0; mi < 4; ++mi) {
        #pragma unroll
        for (int r = 0; r < 4; ++r) {
            unsigned k0 = key32(acc[mi][0][r], encbase);
            unsigned k1 = key32(acc[mi][1][r], encbase - 16);
            unsigned k2 = key32(acc[mi][2][r], encbase - 32);
            unsigned k3 = key32(acc[mi][3][r], encbase - 48);
            const unsigned m01 = u32max(k0, k1), n01 = u32min(k0, k1);
            const unsigned m23 = u32max(k2, k3), n23 = u32min(k2, k3);
            const unsigned t1 = u32max(m01, m23);
            const unsigned t2 = u32max(u32min(m01, m23), u32max(n01, n23));
            const int rloc = wr * 64 + mi * 16 + lg * 4 + r;
            uint2 p; p.x = t1; p.y = t2;
            T[rloc * 33 + wc * 16 + lr] = p;
        }
    }
    __syncthreads();

    if (tid < BM) {
        const uint2* rp = T + tid * 33;
        unsigned T1 = 0, T2 = 0;
        #pragma unroll
        for (int i = 0; i < 32; ++i) {
            const uint2 p = rp[i];
            const unsigned n1 = u32max(T1, p.x);
            const unsigned lo = u32min(T1, p.x);
            T2 = u32max(T2, u32max(lo, p.y));
            T1 = n1;
        }
        uint2 o; o.x = T1; o.y = T2;
        *reinterpret_cast<uint2*>(pout + (size_t)(n0 + tid) * 256 + bx * 2) = o;
    }
    #undef STAGE
}

// ---------- fixup: global top-4 candidates -> exact f32 -> argmax + gather ----------
__device__ __forceinline__ unsigned long long expand_key(unsigned k, int blk) {
    const int col = blk * 128 + 127 - (int)(k & 127u);
    return ((unsigned long long)(k & 0xFFFFFF80u) << 32) | (unsigned)(~col);
}

__global__ void k_fixup(const unsigned* pk,  // == (u32*)d_out, intentionally no restrict
                        const float* __restrict__ x, const float* __restrict__ e,
                        float* out) {
    const int row = blockIdx.x;
    const int t   = threadIdx.x;   // 64 lanes; block id == t
    const uint2 kv = reinterpret_cast<const uint2*>(pk + (size_t)row * 256)[t];
    unsigned long long kk0 = expand_key(kv.x, t);
    unsigned long long kk1 = expand_key(kv.y, t);

    int cand[4];
    #pragma unroll
    for (int p = 0; p < 4; ++p) {
        unsigned long long m = kk0 > kk1 ? kk0 : kk1;
        #pragma unroll
        for (int off = 1; off < 64; off <<= 1) {
            const unsigned long long o = __shfl_xor(m, off);
            if (o > m) m = o;
        }
        cand[p] = (int)(~(unsigned)m) & (CCNT - 1);
        if (kk0 == m) kk0 = 0ull;
        if (kk1 == m) kk1 = 0ull;
    }

    const float4 xv = *reinterpret_cast<const float4*>(x + (size_t)row * DDIM + t * 4);
    float best = -INFINITY; int bc = 0x7fffffff;
    #pragma unroll
    for (int p = 0; p < 4; ++p) {
        const int c = cand[p];
        const float4 ev = *reinterpret_cast<const float4*>(e + (size_t)c * DDIM + t * 4);
        float d  = xv.x * ev.x + xv.y * ev.y + xv.z * ev.z + xv.w * ev.w;
        float ss = ev.x * ev.x + ev.y * ev.y + ev.z * ev.z + ev.w * ev.w;
        #pragma unroll
        for (int off = 1; off < 64; off <<= 1) {
            d  += __shfl_xor(d, off);
            ss += __shfl_xor(ss, off);
        }
        const float v = d * (1.0f / fmaxf(sqrtf(ss), 1e-12f));
        if (v > best || (v == best && c < bc)) { best = v; bc = c; }
    }

    if (t == 0) out[(size_t)QROWS * DDIM + row] = (float)bc;
    const float4 q = *reinterpret_cast<const float4*>(e + (size_t)bc * DDIM + t * 4);
    *reinterpret_cast<float4*>(out + (size_t)row * DDIM + t * 4) = q; // overwrites this row's partials only
}

extern "C" void kernel_launch(void* const* d_in, const int* in_sizes, int n_in,
                              void* d_out, int out_size, void* d_ws, size_t ws_size,
                              hipStream_t stream) {
    const float* x = (const float*)d_in[0];
    const float* e = (const float*)d_in[1];
    float* out = (float*)d_out;
    char* ws = (char*)d_ws;

    unsigned short* xb = (unsigned short*)ws;                             // 4 MB
    unsigned short* eb = (unsigned short*)(ws + (size_t)4 * 1024 * 1024); // 4 MB

    k_prep_x<<<QROWS * DDIM / (256 * 8), 256, 0, stream>>>(x, xb);
    k_prep_e<<<CCNT / 4, 256, 0, stream>>>(e, eb);
    dim3 g2(CBLKS, QROWS / BM);
    k_gemm<<<g2, 256, 0, stream>>>(xb, eb, (unsigned*)d_out);
    k_fixup<<<QROWS, 64, 0, stream>>>((const unsigned*)d_out, x, e, out);
}

// Round 4
// 65.542 us; speedup vs baseline: 7.1489x; 1.0895x over previous
//
#include <hip/hip_runtime.h>
#include <math.h>

// B=8, N=1024, D=256, C=8192
#define QROWS 8192
#define DDIM  256
#define CCNT  8192
#define BM    128
#define BN    128
#define BK    64
#define CBLKS (CCNT / BN)    // 64

typedef __attribute__((ext_vector_type(4))) float f32x4;
typedef __attribute__((ext_vector_type(8))) short bf16x8;

__device__ __forceinline__ unsigned short f2bf(float f) {
    unsigned u = __float_as_uint(f);
    u += 0x7fffu + ((u >> 16) & 1u);          // round-to-nearest-even
    return (unsigned short)(u >> 16);
}
__device__ __forceinline__ unsigned u32max(unsigned a, unsigned b) { return a > b ? a : b; }
__device__ __forceinline__ unsigned u32min(unsigned a, unsigned b) { return a < b ? a : b; }

// u32 key: 25-bit monotone float + 7-bit (127 - local_col); bigger = better, lower col wins ties
__device__ __forceinline__ unsigned key32(float v, unsigned enc) {
    unsigned u = __float_as_uint(v);
    unsigned s = (unsigned)((int)u >> 31);
    return ((u ^ (s | 0x80000000u)) & 0xFFFFFF80u) | enc;
}

// ---------- merged prep: x -> bf16 ; e -> l2-normalized bf16 ----------
__global__ void k_prep(const float* __restrict__ x, unsigned short* __restrict__ xb,
                       const float* __restrict__ e, unsigned short* __restrict__ eb) {
    const int bid = blockIdx.x;
    if (bid < 1024) {                         // x: 1024 blocks, 8 el/thread
        const int i = (bid * 256 + threadIdx.x) * 8;
        const float4 f0 = *reinterpret_cast<const float4*>(x + i);
        const float4 f1 = *reinterpret_cast<const float4*>(x + i + 4);
        uint4 o;
        o.x = f2bf(f0.x) | ((unsigned)f2bf(f0.y) << 16);
        o.y = f2bf(f0.z) | ((unsigned)f2bf(f0.w) << 16);
        o.z = f2bf(f1.x) | ((unsigned)f2bf(f1.y) << 16);
        o.w = f2bf(f1.z) | ((unsigned)f2bf(f1.w) << 16);
        *reinterpret_cast<uint4*>(xb + i) = o;
    } else {                                  // e: 2048 blocks, 4 rows/block
        const int row  = (bid - 1024) * 4 + (threadIdx.x >> 6);
        const int lane = threadIdx.x & 63;
        const float4 v = *reinterpret_cast<const float4*>(e + (size_t)row * DDIM + lane * 4);
        float s = v.x * v.x + v.y * v.y + v.z * v.z + v.w * v.w;
        #pragma unroll
        for (int off = 1; off < 64; off <<= 1) s += __shfl_xor(s, off);
        const float inv = 1.0f / fmaxf(sqrtf(s), 1e-12f);
        ushort4 o;
        o.x = f2bf(v.x * inv); o.y = f2bf(v.y * inv);
        o.z = f2bf(v.z * inv); o.w = f2bf(v.w * inv);
        *reinterpret_cast<ushort4*>(eb + (size_t)row * DDIM + lane * 4) = o;
    }
}

#define GLOAD_LDS(g, s) \
    __builtin_amdgcn_global_load_lds((const __attribute__((address_space(1))) void*)(g), \
                                     (__attribute__((address_space(3))) void*)(s), 16, 0, 0)

#define SBAR do { asm volatile("" ::: "memory"); __builtin_amdgcn_s_barrier(); \
                  asm volatile("" ::: "memory"); } while (0)
#define WAIT_LGKM0 do { asm volatile("s_waitcnt lgkmcnt(0)" ::: "memory"); \
                        __builtin_amdgcn_sched_barrier(0); } while (0)
#define WAIT_VM8 do { asm volatile("s_waitcnt vmcnt(8)" ::: "memory"); \
                      __builtin_amdgcn_sched_barrier(0); } while (0)
#define WAIT_VM0 do { asm volatile("s_waitcnt vmcnt(0)" ::: "memory"); \
                      __builtin_amdgcn_sched_barrier(0); } while (0)

// ---------- bf16 MFMA GEMM: BK=64, counted-vmcnt dbuf, XOR-swizzled LDS ----------
__launch_bounds__(256)
__global__ void k_gemm(const unsigned short* __restrict__ xb,
                       const unsigned short* __restrict__ eb,
                       unsigned* pout /* aliases d_out */) {
    // A0 @0, A1 @16384, B0 @32768, B1 @49152 (16 KB each); epilogue T reuses [0,33792)
    __shared__ __align__(16) char smem[65536];

    const int tid = threadIdx.x;
    const int w = tid >> 6, l = tid & 63;
    const int wr = w >> 1, wc = w & 1;        // wave tile: rows wr*64, cols wc*64
    const int lg = l >> 4, lr = l & 15;
    const int bx = blockIdx.x, by = blockIdx.y;
    const int n0 = by * BM, c0 = bx * BN;

    const f32x4 zero = {0.f, 0.f, 0.f, 0.f};
    f32x4 acc[4][4];
    #pragma unroll
    for (int i = 0; i < 4; ++i)
        #pragma unroll
        for (int j = 0; j < 4; ++j) acc[i][j] = zero;

    // ---- staging: tile = 128 rows x 128 B; LDS linear; SOURCE pre-swizzled (rule 21) ----
    // LDS chunk (row, p) holds global chunk (row, p ^ (row&7)); dest = linear lane*16
    const int srow = tid >> 3;                         // row within 32-row group
    const int swzp = (tid & 7) ^ (srow & 7);           // pre-swizzled source chunk
    const char* gA = (const char*)xb + (size_t)(n0 + srow) * 512 + swzp * 16;
    const char* gB = (const char*)eb + (size_t)(c0 + srow) * 512 + swzp * 16;
    const int wb = w * 1024;                           // wave-uniform LDS chunk base

    // 8 gloads per stage: 4x(32 rows) for A, same for B; kb = k-step byte offset (s*128)
#define STAGE(Ab, Bb, kb) do {                                          \
    GLOAD_LDS(gA + (kb),         smem + (Ab) + 0 * 4096 + wb);          \
    GLOAD_LDS(gA + (kb) + 16384, smem + (Ab) + 1 * 4096 + wb);          \
    GLOAD_LDS(gA + (kb) + 32768, smem + (Ab) + 2 * 4096 + wb);          \
    GLOAD_LDS(gA + (kb) + 49152, smem + (Ab) + 3 * 4096 + wb);          \
    GLOAD_LDS(gB + (kb),         smem + (Bb) + 0 * 4096 + wb);          \
    GLOAD_LDS(gB + (kb) + 16384, smem + (Bb) + 1 * 4096 + wb);          \
    GLOAD_LDS(gB + (kb) + 32768, smem + (Bb) + 2 * 4096 + wb);          \
    GLOAD_LDS(gB + (kb) + 49152, smem + (Bb) + 3 * 4096 + wb);          \
} while (0)

    // ---- fragment reads: swizzled chunk offset (row&7 == lr&7 since 16|mi off) ----
    const int aoff = (wr * 64 + lr) * 128;
    const int boff = (wc * 64 + lr) * 128;
    const int k0 = ((0 + lg) ^ (lr & 7)) * 16;         // kk=0 chunk
    const int k1 = ((4 + lg) ^ (lr & 7)) * 16;         // kk=1 chunk

    bf16x8 a[4][2], b[4][2];
#define READS(Ab, Bb) do {                                                           \
    _Pragma("unroll") for (int mi = 0; mi < 4; ++mi) {                               \
        a[mi][0] = *reinterpret_cast<const bf16x8*>(smem + (Ab) + aoff + mi * 2048 + k0); \
        a[mi][1] = *reinterpret_cast<const bf16x8*>(smem + (Ab) + aoff + mi * 2048 + k1); \
    }                                                                                \
    _Pragma("unroll") for (int nj = 0; nj < 4; ++nj) {                               \
        b[nj][0] = *reinterpret_cast<const bf16x8*>(smem + (Bb) + boff + nj * 2048 + k0); \
        b[nj][1] = *reinterpret_cast<const bf16x8*>(smem + (Bb) + boff + nj * 2048 + k1); \
    }                                                                                \
} while (0)

#define MMAS() do {                                                     \
    __builtin_amdgcn_s_setprio(1);                                      \
    _Pragma("unroll") for (int kk = 0; kk < 2; ++kk)                    \
      _Pragma("unroll") for (int mi = 0; mi < 4; ++mi)                  \
        _Pragma("unroll") for (int nj = 0; nj < 4; ++nj)                \
          acc[mi][nj] = __builtin_amdgcn_mfma_f32_16x16x32_bf16(a[mi][kk], b[nj][kk], acc[mi][nj], 0, 0, 0); \
    __builtin_amdgcn_s_setprio(0);                                      \
} while (0)

    // ---- pipeline: stage-for-s lands one full iteration ahead; vmcnt never 0 mid-loop ----
    STAGE(0, 32768, 0);          // k-step 0 -> buf0
    STAGE(16384, 49152, 128);    // k-step 1 -> buf1
    WAIT_VM8; SBAR;              // step0 landed on all waves

    // iter 0 (buf0)
    READS(0, 32768);
    WAIT_LGKM0; SBAR;            // all reads of buf0 done -> may overwrite
    STAGE(0, 32768, 256);        // k-step 2 -> buf0
    MMAS();
    WAIT_VM8; SBAR;              // step1 landed
    // iter 1 (buf1)
    READS(16384, 49152);
    WAIT_LGKM0; SBAR;
    STAGE(16384, 49152, 384);    // k-step 3 -> buf1
    MMAS();
    WAIT_VM8; SBAR;              // step2 landed
    // iter 2 (buf0)
    READS(0, 32768);
    WAIT_LGKM0; SBAR;
    MMAS();
    WAIT_VM0; SBAR;              // step3 landed (drain: nothing else in flight)
    // iter 3 (buf1)
    READS(16384, 49152);
    WAIT_LGKM0;
    MMAS();
    __syncthreads();             // before smem reuse as epilogue table

    // ---- epilogue: per-lane top2-of-4 u32 keys -> LDS table -> per-row scan ----
    uint2* T = (uint2*)smem;                    // [128][33] padded
    const unsigned encbase = (unsigned)(127 - wc * 64 - lr);
    #pragma unroll
    for (int mi = 0; mi < 4; ++mi) {
        #pragma unroll
        for (int r = 0; r < 4; ++r) {
            unsigned q0 = key32(acc[mi][0][r], encbase);
            unsigned q1 = key32(acc[mi][1][r], encbase - 16);
            unsigned q2 = key32(acc[mi][2][r], encbase - 32);
            unsigned q3 = key32(acc[mi][3][r], encbase - 48);
            const unsigned m01 = u32max(q0, q1), n01 = u32min(q0, q1);
            const unsigned m23 = u32max(q2, q3), n23 = u32min(q2, q3);
            const unsigned t1 = u32max(m01, m23);
            const unsigned t2 = u32max(u32min(m01, m23), u32max(n01, n23));
            const int rloc = wr * 64 + mi * 16 + lg * 4 + r;
            uint2 p; p.x = t1; p.y = t2;
            T[rloc * 33 + wc * 16 + lr] = p;
        }
    }
    __syncthreads();

    if (tid < BM) {
        const uint2* rp = T + tid * 33;
        unsigned T1 = 0, T2 = 0;
        #pragma unroll
        for (int i = 0; i < 32; ++i) {
            const uint2 p = rp[i];
            const unsigned n1 = u32max(T1, p.x);
            const unsigned lo = u32min(T1, p.x);
            T2 = u32max(T2, u32max(lo, p.y));
            T1 = n1;
        }
        uint2 o; o.x = T1; o.y = T2;
        *reinterpret_cast<uint2*>(pout + (size_t)(n0 + tid) * 256 + bx * 2) = o;
    }
#undef STAGE
#undef READS
#undef MMAS
}

// ---------- fixup: global top-4 candidates -> exact f32 -> argmax + gather ----------
__device__ __forceinline__ unsigned long long expand_key(unsigned k, int blk) {
    const int col = blk * 128 + 127 - (int)(k & 127u);
    return ((unsigned long long)(k & 0xFFFFFF80u) << 32) | (unsigned)(~col);
}

__global__ void k_fixup(const unsigned* pk,  // == (u32*)d_out, intentionally no restrict
                        const float* __restrict__ x, const float* __restrict__ e,
                        float* out) {
    const int row = blockIdx.x * 4 + (threadIdx.x >> 6);
    const int t   = threadIdx.x & 63;   // 64 lanes; col-block id == t
    const uint2 kv = reinterpret_cast<const uint2*>(pk + (size_t)row * 256)[t];
    unsigned long long kk0 = expand_key(kv.x, t);
    unsigned long long kk1 = expand_key(kv.y, t);

    int cand[4];
    #pragma unroll
    for (int p = 0; p < 4; ++p) {
        unsigned long long m = kk0 > kk1 ? kk0 : kk1;
        #pragma unroll
        for (int off = 1; off < 64; off <<= 1) {
            const unsigned long long o = __shfl_xor(m, off);
            if (o > m) m = o;
        }
        cand[p] = (int)(~(unsigned)m) & (CCNT - 1);
        if (kk0 == m) kk0 = 0ull;
        if (kk1 == m) kk1 = 0ull;
    }

    const float4 xv = *reinterpret_cast<const float4*>(x + (size_t)row * DDIM + t * 4);
    float best = -INFINITY; int bc = 0x7fffffff;
    #pragma unroll
    for (int p = 0; p < 4; ++p) {
        const int c = cand[p];
        const float4 ev = *reinterpret_cast<const float4*>(e + (size_t)c * DDIM + t * 4);
        float d  = xv.x * ev.x + xv.y * ev.y + xv.z * ev.z + xv.w * ev.w;
        float ss = ev.x * ev.x + ev.y * ev.y + ev.z * ev.z + ev.w * ev.w;
        #pragma unroll
        for (int off = 1; off < 64; off <<= 1) {
            d  += __shfl_xor(d, off);
            ss += __shfl_xor(ss, off);
        }
        const float v = d * (1.0f / fmaxf(sqrtf(ss), 1e-12f));
        if (v > best || (v == best && c < bc)) { best = v; bc = c; }
    }

    if (t == 0) out[(size_t)QROWS * DDIM + row] = (float)bc;
    const float4 q = *reinterpret_cast<const float4*>(e + (size_t)bc * DDIM + t * 4);
    *reinterpret_cast<float4*>(out + (size_t)row * DDIM + t * 4) = q; // overwrites this row's partials only
}

extern "C" void kernel_launch(void* const* d_in, const int* in_sizes, int n_in,
                              void* d_out, int out_size, void* d_ws, size_t ws_size,
                              hipStream_t stream) {
    const float* x = (const float*)d_in[0];
    const float* e = (const float*)d_in[1];
    float* out = (float*)d_out;
    char* ws = (char*)d_ws;

    unsigned short* xb = (unsigned short*)ws;                             // 4 MB
    unsigned short* eb = (unsigned short*)(ws + (size_t)4 * 1024 * 1024); // 4 MB

    k_prep<<<3072, 256, 0, stream>>>(x, xb, e, eb);
    dim3 g2(CBLKS, QROWS / BM);
    k_gemm<<<g2, 256, 0, stream>>>(xb, eb, (unsigned*)d_out);
    k_fixup<<<QROWS / 4, 256, 0, stream>>>((const unsigned*)d_out, x, e, out);
}